// Round 8
// baseline (2347.004 us; speedup 1.0000x reference)
//
#include <hip/hip_runtime.h>

typedef unsigned short u16;
typedef unsigned int u32;
typedef _Float16 f16;
typedef f16 f16x8 __attribute__((ext_vector_type(8)));
typedef float f32x4 __attribute__((ext_vector_type(4)));

constexpr int N_NODES = 50000;
constexpr int E_EDGES = 800000;
constexpr int NBINS   = 50176;            // 196 * 256
constexpr int NBLK    = 196;

// workspace layout (bytes)
constexpr size_t OFF_DEG   = 0;           // NBINS*4
constexpr size_t OFF_LOCEX = 200704;
constexpr size_t OFF_BSUM  = 401408;
constexpr size_t OFF_BOFF  = 402432;
constexpr size_t OFF_FILL  = 403456;
constexpr size_t OFF_SCAT  = 604160;      // N*2*4
constexpr size_t OFF_SROW  = 1004160;     // E*4
constexpr size_t OFF_SCOL  = 4204160;     // E*4
constexpr size_t NH_BYTES  = (size_t)N_NODES * 128 * 4;   // 25,600,000
constexpr size_t OFF_H     = 7404160;                     // h f32
constexpr size_t OFF_ZS    = OFF_H  + NH_BYTES;           // zsum f32
constexpr size_t OFF_A     = OFF_ZS + NH_BYTES;           // a f32
constexpr size_t OFF_B     = OFF_A  + NH_BYTES;           // b f32
constexpr size_t OFF_W     = OFF_B  + NH_BYTES;           // swizzled weights

__device__ __forceinline__ void split_f(float x, f16& h, f16& l) {
    h = (f16)x;
    l = (f16)(x - (float)h);
}

__device__ __forceinline__ f32x4 mfma3(f16x8 ah, f16x8 al, f16x8 bh, f16x8 bl, f32x4 acc) {
    acc = __builtin_amdgcn_mfma_f32_16x16x32_f16(ah, bh, acc, 0, 0, 0);
    acc = __builtin_amdgcn_mfma_f32_16x16x32_f16(al, bh, acc, 0, 0, 0);
    acc = __builtin_amdgcn_mfma_f32_16x16x32_f16(ah, bl, acc, 0, 0, 0);
    return acc;
}

// ---- prep: swizzle weights into fragment-order hi/lo f16 planes ----
__global__ __launch_bounds__(256) void prep_kernel(
    const float* __restrict__ eW1, const float* __restrict__ eW2,
    const float* __restrict__ nW1, const float* __restrict__ nW2,
    const float* __restrict__ vW1, const float* __restrict__ cW1,
    f16* __restrict__ W1ts, f16* __restrict__ W1ms,
    f16* __restrict__ nW1s, f16* __restrict__ eW2s,
    f16* __restrict__ nW2s, f16* __restrict__ vW1s, f16* __restrict__ cW1s)
{
    const int gid = blockIdx.x * 256 + threadIdx.x;   // 131072 total
    const float* W; f16* out; int K32; int e; int krow_off = 0;
    if (gid < 16384)       { W = eW1; out = W1ts; K32 = 4; e = gid; }
    else if (gid < 32768)  { W = eW1; out = W1ms; K32 = 4; e = gid - 16384; krow_off = 128; }
    else if (gid < 65536)  { W = nW1; out = nW1s; K32 = 8; e = gid - 32768; }
    else if (gid < 81920)  { W = eW2; out = eW2s; K32 = 4; e = gid - 65536; }
    else if (gid < 98304)  { W = nW2; out = nW2s; K32 = 4; e = gid - 81920; }
    else if (gid < 114688) { W = vW1; out = vW1s; K32 = 4; e = gid - 98304; }
    else                   { W = cW1; out = cW1s; K32 = 4; e = gid - 114688; }
    const int per = 512 * K32;
    const int ct = e / per, rem = e % per;
    const int kk = rem >> 9, lane = (rem >> 3) & 63, j = rem & 7;
    const int col = ct * 16 + (lane & 15);
    const int k = kk * 32 + ((lane >> 4) & 3) * 8 + j + krow_off;
    const float v = W[k * 128 + col];
    f16 h, l; split_f(v, h, l);
    const int base = ((ct * K32 + kk) * 2) * 512 + lane * 8 + j;
    out[base] = h;
    out[base + 512] = l;
}

// ---- sort pipeline ----
__global__ __launch_bounds__(256) void hist_kernel(const int* __restrict__ eidx,
                                                   int* __restrict__ deg) {
    const int e = blockIdx.x * 256 + threadIdx.x;
    if (e < E_EDGES) atomicAdd(&deg[eidx[e]], 1);
}

__global__ __launch_bounds__(256) void scan1_kernel(const int* __restrict__ deg,
                                                    int* __restrict__ locEx,
                                                    int* __restrict__ blockSum) {
    __shared__ int s[256];
    const int t = threadIdx.x;
    const int gid = blockIdx.x * 256 + t;
    const int v = deg[gid];
    s[t] = v;
    __syncthreads();
    for (int off = 1; off < 256; off <<= 1) {
        const int add = (t >= off) ? s[t - off] : 0;
        __syncthreads();
        s[t] += add;
        __syncthreads();
    }
    locEx[gid] = s[t] - v;
    if (t == 255) blockSum[blockIdx.x] = s[255];
}

__global__ __launch_bounds__(256) void scan2_kernel(const int* __restrict__ blockSum,
                                                    int* __restrict__ blockOff) {
    __shared__ int s[256];
    const int t = threadIdx.x;
    const int v = (t < NBLK) ? blockSum[t] : 0;
    s[t] = v;
    __syncthreads();
    for (int off = 1; off < 256; off <<= 1) {
        const int add = (t >= off) ? s[t - off] : 0;
        __syncthreads();
        s[t] += add;
        __syncthreads();
    }
    if (t < NBLK) blockOff[t] = s[t] - v;
}

__global__ __launch_bounds__(256) void scatter_kernel(const int* __restrict__ eidx,
        const int* __restrict__ locEx, const int* __restrict__ blockOff,
        int* __restrict__ fill, int* __restrict__ srow, int* __restrict__ scol) {
    const int e = blockIdx.x * 256 + threadIdx.x;
    if (e >= E_EDGES) return;
    const int r = eidx[e], c = eidx[E_EDGES + e];
    const int pos = blockOff[r >> 8] + locEx[r] + atomicAdd(&fill[r], 1);
    srow[pos] = r;
    scol[pos] = c;
}

// ---- embedding ----
__global__ __launch_bounds__(256) void embed_kernel(
    const float* __restrict__ h_in, const float* __restrict__ embW,
    const float* __restrict__ embb, float* __restrict__ h)
{
    const int gid = blockIdx.x * 256 + threadIdx.x;
    if (gid >= N_NODES * 128) return;
    const int n = gid >> 7, j = gid & 127;
    float s = embb[j];
#pragma unroll
    for (int p = 0; p < 16; ++p) s += h_in[n * 16 + p] * embW[p * 128 + j];
    h[gid] = s;
}

__device__ __forceinline__ void stage8(const float* src, f16* dst) {
    const float4 f0 = *(const float4*)src;
    const float4 f1 = *(const float4*)(src + 4);
    const float xs[8] = {f0.x, f0.y, f0.z, f0.w, f1.x, f1.y, f1.z, f1.w};
    f16x8 vh, vl;
#pragma unroll
    for (int i = 0; i < 8; ++i) { f16 hh, ll; split_f(xs[i], hh, ll); vh[i] = hh; vl[i] = ll; }
    *(f16x8*)dst = vh;
    *(f16x8*)(dst + 8) = vl;
}

constexpr int S = 264;

__device__ __forceinline__ void stage_tile_f32(const float* __restrict__ src,
                                               int base, f16* smA, int t) {
#pragma unroll
    for (int it = 0; it < 4; ++it) {
        const int idx = it * 256 + t;
        const int el = idx >> 4, seg = idx & 15;
        const int node = base + el;
        f16* dst = &smA[el * S + seg * 16];
        if (node < N_NODES) {
            stage8(src + (size_t)node * 128 + seg * 8, dst);
        } else {
            *(f16x8*)dst = (f16x8)(f16)0.f;
            *(f16x8*)(dst + 8) = (f16x8)(f16)0.f;
        }
    }
}

__device__ __forceinline__ void gemm_k128(const f16* smA, const f16* __restrict__ Ws,
                                          int w, int lane, int qq, int nn,
                                          f32x4 acc[4][2]) {
    for (int kk = 0; kk < 4; ++kk) {
        f16x8 Ah[4], Al[4];
#pragma unroll
        for (int rt = 0; rt < 4; ++rt) {
            const f16* ap = &smA[(rt * 16 + nn) * S + (kk * 4 + qq) * 16];
            Ah[rt] = *(const f16x8*)ap;
            Al[rt] = *(const f16x8*)(ap + 8);
        }
#pragma unroll
        for (int c = 0; c < 2; ++c) {
            const int ct = w * 2 + c;
            const f16* bp = Ws + (size_t)((ct * 4 + kk) * 2) * 512 + lane * 8;
            const f16x8 Bh = *(const f16x8*)bp;
            const f16x8 Bl = *(const f16x8*)(bp + 512);
#pragma unroll
            for (int rt = 0; rt < 4; ++rt)
                acc[rt][c] = mfma3(Ah[rt], Al[rt], Bh, Bl, acc[rt][c]);
        }
    }
}

// ---- zsum kernel: node-tiled; 8-deep batched gather; LDS accumulate only. ----
__global__ __launch_bounds__(256, 4) void zsum_kernel(
    const int* __restrict__ srow, const int* __restrict__ scol,
    const float* __restrict__ x,
    const float* __restrict__ a, const float* __restrict__ b,
    const float* __restrict__ eW1,
    const int* __restrict__ locEx, const int* __restrict__ boff,
    float* __restrict__ zsum)
{
    __shared__ float sA[33 * 128];    // rows 0..31 real, row 32 = trash pad
    __shared__ float sZ[33 * 128];
    __shared__ int   sSlotC[256];     // slot*128
    __shared__ int   sCol[256];
    __shared__ float sRd[256];

    const int t = threadIdx.x;
    const int base = blockIdx.x * 32;
    const int c = t & 127;
    const int half = t >> 7;          // wave-uniform
    const float wl = eW1[256 * 128 + c];

#pragma unroll
    for (int i = 0; i < 17; ++i) {
        const int idx = i * 256 + t;
        if (idx < 33 * 128) {
            const int n = base + (idx >> 7);
            sA[idx] = (idx < 32 * 128 && n < N_NODES)
                      ? a[(size_t)n * 128 + (idx & 127)] : 0.f;
            sZ[idx] = 0.f;
        }
    }
    const int est  = boff[base >> 8] + locEx[base];
    const int eend = boff[(base + 32) >> 8] + locEx[base + 32];

    for (int w0 = est; w0 < eend; w0 += 256) {
        const int wn = min(256, eend - w0);
        __syncthreads();                    // prev window consumers done (+ init)
        {
            const int e = w0 + t;
            if (t < wn) {
                const int r = srow[e], cc = scol[e];
                sSlotC[t] = (r - base) * 128;
                sCol[t] = cc;
                const float dx = x[2 * r] - x[2 * cc];
                const float dy = x[2 * r + 1] - x[2 * cc + 1];
                sRd[t] = dx * dx + dy * dy;
            } else {
                sSlotC[t] = 32 * 128;       // trash row
                sCol[t] = 0;
                sRd[t] = 0.f;
            }
        }
        __syncthreads();
        // 128 edges per half-group, 8-deep batched gather for MLP
        for (int jb = 0; jb < 128; jb += 8) {
            float bv[8], rd[8]; int sl[8];
#pragma unroll
            for (int k = 0; k < 8; ++k) {
                const int es = (jb + k) * 2 + half;
                sl[k] = sSlotC[es] + c;
                rd[k] = sRd[es];
                bv[k] = b[(size_t)sCol[es] * 128 + c];
            }
#pragma unroll
            for (int k = 0; k < 8; ++k) {
                const float z = fmaxf(sA[sl[k]] + bv[k] + rd[k] * wl, 0.f);
                atomicAdd(&sZ[sl[k]], z);
            }
        }
    }
    __syncthreads();
#pragma unroll
    for (int i = 0; i < 16; ++i) {
        const int idx = i * 256 + t;
        const int n = base + (idx >> 7);
        if (n < N_NODES) zsum[(size_t)n * 128 + (idx & 127)] = sZ[idx];
    }
}

// ---- coord kernel (layer 2 only): edge-tiled; z from a/b (VALU), GEMM2+GEMM3 ----
__global__ __launch_bounds__(256, 4) void coord_kernel(
    const int* __restrict__ srow, const int* __restrict__ scol,
    const float* __restrict__ x,
    const float* __restrict__ a, const float* __restrict__ b,
    const float* __restrict__ eW1,
    const f16* __restrict__ eW2s, const float* __restrict__ eb2,
    const f16* __restrict__ cW1s, const float* __restrict__ cb1,
    const float* __restrict__ cW2, const float* __restrict__ cb2,
    float* __restrict__ scat)
{
    __shared__ f16 smZ[64 * S];        // z-split -> m-split (aliased)
    __shared__ int smRow[64], smCol[64];
    __shared__ float smRd[64], smP2x[64], smP2y[64];
    __shared__ float smPart[4][64];

    const int t = threadIdx.x;
    const int base = blockIdx.x * 64;
    const int lane = t & 63, w = t >> 6, qq = lane >> 4, nn = lane & 15;

    if (t < 64) {
        const int e = base + t;
        const int r = srow[e], cc = scol[e];
        smRow[t] = r; smCol[t] = cc;
        const float dx = x[2 * r] - x[2 * cc];
        const float dy = x[2 * r + 1] - x[2 * cc + 1];
        smRd[t] = dx * dx + dy * dy;
        smP2x[t] = dx * dx - dy * dy;
        smP2y[t] = 2.0f * dx * dy;
    }
    __syncthreads();

    // stage z = relu(a_row + b_col + rd*wl), 8-deep batched gathers
    const int c = t & 127;
    const int half = t >> 7;
    const float wl = eW1[256 * 128 + c];
    for (int jb = 0; jb < 32; jb += 8) {
        float av[8], bv[8];
#pragma unroll
        for (int k = 0; k < 8; ++k) {
            const int el = (jb + k) * 2 + half;
            av[k] = a[(size_t)smRow[el] * 128 + c];
            bv[k] = b[(size_t)smCol[el] * 128 + c];
        }
#pragma unroll
        for (int k = 0; k < 8; ++k) {
            const int el = (jb + k) * 2 + half;
            const float z = fmaxf(av[k] + bv[k] + smRd[el] * wl, 0.f);
            f16 zh, zl; split_f(z, zh, zl);
            f16* zp = &smZ[el * S + (c >> 3) * 16 + (c & 7)];
            zp[0] = zh; zp[8] = zl;
        }
    }
    __syncthreads();

    // GEMM2: m = z @ eW2 + eb2
    f32x4 acc2[4][2] = {};
    gemm_k128(smZ, eW2s, w, lane, qq, nn, acc2);
    __syncthreads();                       // z reads done -> m may overwrite
#pragma unroll
    for (int cc = 0; cc < 2; ++cc) {
        const int col = w * 32 + cc * 16 + nn;
        const float b2 = eb2[col];
#pragma unroll
        for (int rt = 0; rt < 4; ++rt) {
#pragma unroll
            for (int r = 0; r < 4; ++r) {
                const int el = rt * 16 + qq * 4 + r;
                const float mv = acc2[rt][cc][r] + b2;
                f16 mh, ml; split_f(mv, mh, ml);
                f16* mp = &smZ[el * S + (col >> 3) * 16 + (col & 7)];
                mp[0] = mh; mp[8] = ml;
            }
        }
    }
    __syncthreads();

    // GEMM3: co = relu(m @ cW1 + cb1) @ cW2 + cb2
    f32x4 acc3[4][2] = {};
    gemm_k128(smZ, cW1s, w, lane, qq, nn, acc3);
    float p3[4][4];
#pragma unroll
    for (int rt = 0; rt < 4; ++rt)
#pragma unroll
        for (int r = 0; r < 4; ++r) p3[rt][r] = 0.f;
#pragma unroll
    for (int cc = 0; cc < 2; ++cc) {
        const int col = w * 32 + cc * 16 + nn;
        const float c1 = cb1[col];
        const float w2 = cW2[col];
#pragma unroll
        for (int rt = 0; rt < 4; ++rt)
#pragma unroll
            for (int r = 0; r < 4; ++r)
                p3[rt][r] += fmaxf(acc3[rt][cc][r] + c1, 0.f) * w2;
    }
#pragma unroll
    for (int off = 1; off < 16; off <<= 1)
#pragma unroll
        for (int rt = 0; rt < 4; ++rt)
#pragma unroll
            for (int r = 0; r < 4; ++r) p3[rt][r] += __shfl_xor(p3[rt][r], off);
    if (nn == 0) {
#pragma unroll
        for (int rt = 0; rt < 4; ++rt)
#pragma unroll
            for (int r = 0; r < 4; ++r)
                smPart[w][rt * 16 + qq * 4 + r] = p3[rt][r];
    }
    __syncthreads();
    if (t < 64) {
        const float co = smPart[0][t] + smPart[1][t] + smPart[2][t] + smPart[3][t] + cb2[0];
        const int rw = smRow[t];
        atomicAdd(&scat[2 * rw],     smP2x[t] * co);
        atomicAdd(&scat[2 * rw + 1], smP2y[t] * co);
    }
}

// ---- node kernel: mode 0: a,b precompute. mode 1: h update + a,b.
//      mode 2: h update + fused final. ----
__global__ __launch_bounds__(256, 4) void node_kernel(
    float* __restrict__ h, const float* __restrict__ zsum,
    const int* __restrict__ deg,
    const f16* __restrict__ eW2s, const float* __restrict__ eb2,
    const f16* __restrict__ nW1s, const float* __restrict__ nb1,
    const f16* __restrict__ nW2s, const float* __restrict__ nb2,
    const f16* __restrict__ W1ts, const f16* __restrict__ W1ms,
    const float* __restrict__ eb1,
    const f16* __restrict__ vW1s, const float* __restrict__ vb1,
    const float* __restrict__ vW2, const float* __restrict__ vb2,
    const float* __restrict__ scat, const float* __restrict__ x,
    float* __restrict__ a, float* __restrict__ b,
    float* __restrict__ out, const int mode)
{
    __shared__ f16 smA[64 * S];
    const int t = threadIdx.x;
    const int base = blockIdx.x * 64;
    const int lane = t & 63, w = t >> 6, qq = lane >> 4, nn = lane & 15;

    float hv[4][2][4];

    if (mode >= 1) {
        stage_tile_f32(zsum, base, smA, t);
        __syncthreads();
        f32x4 accm[4][2] = {};
        gemm_k128(smA, eW2s, w, lane, qq, nn, accm);
        __syncthreads();

        stage_tile_f32(h, base, smA, t);
        __syncthreads();

        f32x4 acc1[4][2] = {};
        for (int kk = 0; kk < 4; ++kk) {
            f16x8 Ah[4], Al[4];
#pragma unroll
            for (int rt = 0; rt < 4; ++rt) {
                const f16* ap = &smA[(rt * 16 + nn) * S + (kk * 4 + qq) * 16];
                Ah[rt] = *(const f16x8*)ap;
                Al[rt] = *(const f16x8*)(ap + 8);
            }
#pragma unroll
            for (int c = 0; c < 2; ++c) {
                const int ct = w * 2 + c;
                const f16* bp = nW1s + (size_t)((ct * 8 + kk) * 2) * 512 + lane * 8;
                const f16x8 Bh = *(const f16x8*)bp;
                const f16x8 Bl = *(const f16x8*)(bp + 512);
#pragma unroll
                for (int rt = 0; rt < 4; ++rt)
                    acc1[rt][c] = mfma3(Ah[rt], Al[rt], Bh, Bl, acc1[rt][c]);
            }
        }
        __syncthreads();
#pragma unroll
        for (int c = 0; c < 2; ++c) {
            const int col = w * 32 + c * 16 + nn;
            const float b2 = eb2[col];
#pragma unroll
            for (int rt = 0; rt < 4; ++rt) {
#pragma unroll
                for (int r = 0; r < 4; ++r) {
                    const int el = rt * 16 + qq * 4 + r;
                    const int node = base + el;
                    const float dg = (node < N_NODES) ? (float)deg[node] : 0.f;
                    const float mv = accm[rt][c][r] + dg * b2;
                    f16 mh, ml; split_f(mv, mh, ml);
                    f16* mp = &smA[el * S + (col >> 3) * 16 + (col & 7)];
                    mp[0] = mh; mp[8] = ml;
                }
            }
        }
        __syncthreads();
        for (int kk = 0; kk < 4; ++kk) {
            f16x8 Ah[4], Al[4];
#pragma unroll
            for (int rt = 0; rt < 4; ++rt) {
                const f16* ap = &smA[(rt * 16 + nn) * S + (kk * 4 + qq) * 16];
                Ah[rt] = *(const f16x8*)ap;
                Al[rt] = *(const f16x8*)(ap + 8);
            }
#pragma unroll
            for (int c = 0; c < 2; ++c) {
                const int ct = w * 2 + c;
                const f16* bp = nW1s + (size_t)((ct * 8 + kk + 4) * 2) * 512 + lane * 8;
                const f16x8 Bh = *(const f16x8*)bp;
                const f16x8 Bl = *(const f16x8*)(bp + 512);
#pragma unroll
                for (int rt = 0; rt < 4; ++rt)
                    acc1[rt][c] = mfma3(Ah[rt], Al[rt], Bh, Bl, acc1[rt][c]);
            }
        }
        __syncthreads();
#pragma unroll
        for (int c = 0; c < 2; ++c) {
            const int col = w * 32 + c * 16 + nn;
            const float b1 = nb1[col];
#pragma unroll
            for (int rt = 0; rt < 4; ++rt) {
#pragma unroll
                for (int r = 0; r < 4; ++r) {
                    const int el = rt * 16 + qq * 4 + r;
                    const float z = fmaxf(acc1[rt][c][r] + b1, 0.f);
                    f16 zh, zl; split_f(z, zh, zl);
                    f16* zp = &smA[el * S + (col >> 3) * 16 + (col & 7)];
                    zp[0] = zh; zp[8] = zl;
                }
            }
        }
        __syncthreads();
        f32x4 acc2[4][2] = {};
        gemm_k128(smA, nW2s, w, lane, qq, nn, acc2);
#pragma unroll
        for (int c = 0; c < 2; ++c) {
            const int col = w * 32 + c * 16 + nn;
            const float b2 = nb2[col];
#pragma unroll
            for (int rt = 0; rt < 4; ++rt) {
#pragma unroll
                for (int r = 0; r < 4; ++r) {
                    const int el = rt * 16 + qq * 4 + r;
                    const int node = base + el;
                    float v = 0.f;
                    if (node < N_NODES)
                        v = h[(size_t)node * 128 + col] + acc2[rt][c][r] + b2;
                    hv[rt][c][r] = v;
                }
            }
        }
        __syncthreads();
        float* hdst = (mode == 1) ? h : out;
#pragma unroll
        for (int c = 0; c < 2; ++c) {
            const int col = w * 32 + c * 16 + nn;
#pragma unroll
            for (int rt = 0; rt < 4; ++rt) {
#pragma unroll
                for (int r = 0; r < 4; ++r) {
                    const int el = rt * 16 + qq * 4 + r;
                    const int node = base + el;
                    if (node < N_NODES)
                        hdst[(size_t)node * 128 + col] = hv[rt][c][r];
                    f16 hh, ll; split_f(hv[rt][c][r], hh, ll);
                    f16* p = &smA[el * S + (col >> 3) * 16 + (col & 7)];
                    p[0] = hh; p[8] = ll;
                }
            }
        }
        __syncthreads();
    } else {
        stage_tile_f32(h, base, smA, t);
        __syncthreads();
    }

    if (mode <= 1) {
        {
            f32x4 acca[4][2] = {};
            gemm_k128(smA, W1ts, w, lane, qq, nn, acca);
#pragma unroll
            for (int c = 0; c < 2; ++c) {
                const int col = w * 32 + c * 16 + nn;
                const float b1 = eb1[col];
#pragma unroll
                for (int rt = 0; rt < 4; ++rt) {
#pragma unroll
                    for (int r = 0; r < 4; ++r) {
                        const int node = base + rt * 16 + qq * 4 + r;
                        if (node < N_NODES)
                            a[(size_t)node * 128 + col] = acca[rt][c][r] + b1;
                    }
                }
            }
        }
        {
            f32x4 accb[4][2] = {};
            gemm_k128(smA, W1ms, w, lane, qq, nn, accb);
#pragma unroll
            for (int c = 0; c < 2; ++c) {
                const int col = w * 32 + c * 16 + nn;
#pragma unroll
                for (int rt = 0; rt < 4; ++rt) {
#pragma unroll
                    for (int r = 0; r < 4; ++r) {
                        const int node = base + rt * 16 + qq * 4 + r;
                        if (node < N_NODES)
                            b[(size_t)node * 128 + col] = accb[rt][c][r];
                    }
                }
            }
        }
    } else {
        float* out_x = out + (size_t)N_NODES * 128;
        float* out_v = out_x + (size_t)N_NODES * 2;
        if (t < 128) {
            const int node = base + (t >> 1);
            if (node < N_NODES) out_x[node * 2 + (t & 1)] = x[node * 2 + (t & 1)];
        }
        f32x4 accv[4][2] = {};
        gemm_k128(smA, vW1s, w, lane, qq, nn, accv);
        __syncthreads();
#pragma unroll
        for (int c = 0; c < 2; ++c) {
            const int col = w * 32 + c * 16 + nn;
            const float b1 = vb1[col];
#pragma unroll
            for (int rt = 0; rt < 4; ++rt) {
#pragma unroll
                for (int r = 0; r < 4; ++r) {
                    const int el = rt * 16 + qq * 4 + r;
                    const float z = fmaxf(accv[rt][c][r] + b1, 0.f);
                    f16 zh, zl; split_f(z, zh, zl);
                    f16* zp = &smA[el * S + (col >> 3) * 16 + (col & 7)];
                    zp[0] = zh; zp[8] = zl;
                }
            }
        }
        __syncthreads();
        if (t < 128) {
            const int rl = t >> 1, comp = t & 1;
            const int node = base + rl;
            float s = 0.f;
            if (node < N_NODES) {
                s = vb2[comp];
                for (int k = 0; k < 128; ++k) {
                    const f16* zp = &smA[rl * S + (k >> 3) * 16 + (k & 7)];
                    s += ((float)zp[0] + (float)zp[8]) * vW2[k * 2 + comp];
                }
                const float dn = fmaxf((float)deg[node], 1.0f);
                s += scat[node * 2 + comp] / dn;
            }
            const float other = __shfl_xor(s, 1);
            if (node < N_NODES) {
                const float nrm = sqrtf(s * s + other * other);
                out_v[node * 2 + comp] = s / fmaxf(nrm, 1e-12f);
            }
        }
    }
}

extern "C" void kernel_launch(void* const* d_in, const int* in_sizes, int n_in,
                              void* d_out, int out_size, void* d_ws, size_t ws_size,
                              hipStream_t stream) {
    const float* h_in = (const float*)d_in[0];
    const float* x    = (const float*)d_in[1];
    const int*   eidx = (const int*)d_in[2];
    const float* embW = (const float*)d_in[3];
    const float* embb = (const float*)d_in[4];
    const float* eW1  = (const float*)d_in[5];
    const float* eb1  = (const float*)d_in[6];
    const float* eW2  = (const float*)d_in[7];
    const float* eb2  = (const float*)d_in[8];
    const float* nW1  = (const float*)d_in[9];
    const float* nb1  = (const float*)d_in[10];
    const float* nW2  = (const float*)d_in[11];
    const float* nb2  = (const float*)d_in[12];
    const float* vW1  = (const float*)d_in[13];
    const float* vb1  = (const float*)d_in[14];
    const float* vW2  = (const float*)d_in[15];
    const float* vb2  = (const float*)d_in[16];
    const float* cW1  = (const float*)d_in[17];
    const float* cb1  = (const float*)d_in[18];
    const float* cW2  = (const float*)d_in[19];
    const float* cb2  = (const float*)d_in[20];

    char* ws = (char*)d_ws;
    int* deg    = (int*)(ws + OFF_DEG);
    int* locEx  = (int*)(ws + OFF_LOCEX);
    int* bsum   = (int*)(ws + OFF_BSUM);
    int* boff   = (int*)(ws + OFF_BOFF);
    int* fill   = (int*)(ws + OFF_FILL);
    float* scat = (float*)(ws + OFF_SCAT);
    int* srow   = (int*)(ws + OFF_SROW);
    int* scol   = (int*)(ws + OFF_SCOL);
    float* h    = (float*)(ws + OFF_H);
    float* zsum = (float*)(ws + OFF_ZS);
    float* a    = (float*)(ws + OFF_A);
    float* b    = (float*)(ws + OFF_B);
    f16* W1ts = (f16*)(ws + OFF_W);
    f16* W1ms = W1ts + 32768;
    f16* nW1s = W1ms + 32768;
    f16* eW2s = nW1s + 65536;
    f16* nW2s = eW2s + 32768;
    f16* vW1s = nW2s + 32768;
    f16* cW1s = vW1s + 32768;

    hipMemsetAsync(ws, 0, OFF_SROW, stream);

    prep_kernel<<<512, 256, 0, stream>>>(eW1, eW2, nW1, nW2, vW1, cW1,
                                         W1ts, W1ms, nW1s, eW2s, nW2s, vW1s, cW1s);
    hist_kernel<<<(E_EDGES + 255) / 256, 256, 0, stream>>>(eidx, deg);
    scan1_kernel<<<NBLK, 256, 0, stream>>>(deg, locEx, bsum);
    scan2_kernel<<<1, 256, 0, stream>>>(bsum, boff);
    scatter_kernel<<<(E_EDGES + 255) / 256, 256, 0, stream>>>(eidx, locEx, boff,
                                                              fill, srow, scol);
    embed_kernel<<<(N_NODES * 128 + 255) / 256, 256, 0, stream>>>(h_in, embW, embb, h);

    const int ngrid = (N_NODES + 63) / 64;   // 782
    const int zgrid = (N_NODES + 31) / 32;   // 1563

    node_kernel<<<ngrid, 256, 0, stream>>>(h, zsum, deg, eW2s, eb2, nW1s, nb1,
        nW2s, nb2, W1ts, W1ms, eb1, vW1s, vb1, vW2, vb2, scat, x,
        a, b, (float*)d_out, 0);

    // layer 1
    zsum_kernel<<<zgrid, 256, 0, stream>>>(srow, scol, x, a, b, eW1,
                                           locEx, boff, zsum);
    node_kernel<<<ngrid, 256, 0, stream>>>(h, zsum, deg, eW2s, eb2, nW1s, nb1,
        nW2s, nb2, W1ts, W1ms, eb1, vW1s, vb1, vW2, vb2, scat, x,
        a, b, (float*)d_out, 1);

    // layer 2
    zsum_kernel<<<zgrid, 256, 0, stream>>>(srow, scol, x, a, b, eW1,
                                           locEx, boff, zsum);
    coord_kernel<<<E_EDGES / 64, 256, 0, stream>>>(srow, scol, x, a, b, eW1,
        eW2s, eb2, cW1s, cb1, cW2, cb2, scat);
    node_kernel<<<ngrid, 256, 0, stream>>>(h, zsum, deg, eW2s, eb2, nW1s, nb1,
        nW2s, nb2, W1ts, W1ms, eb1, vW1s, vb1, vW2, vb2, scat, x,
        a, b, (float*)d_out, 2);
}